// Round 3
// baseline (1718.898 us; speedup 1.0000x reference)
//
#include <hip/hip_runtime.h>

#define D_MODEL 1024
#define N_HEADS 16
#define N_GROUPS 4
#define D_FF 4096
#define N_EXPERTS 8
#define BATCH 2
#define SEQ 1024
#define DK 64
#define NTOK (BATCH*SEQ)
#define KVD (N_GROUPS*DK)
#define BPAD 66   // 32xBPAD LDS B tile: +2 pad spreads k-rows across banks for scalar frag reads

typedef unsigned short u16;
typedef unsigned int u32;
typedef __attribute__((ext_vector_type(8))) short short8;
typedef __attribute__((ext_vector_type(8))) __bf16 bf16x8;
typedef __attribute__((ext_vector_type(4))) float floatx4;

__device__ __forceinline__ float bflo(u32 u){ return __uint_as_float(u<<16); }
__device__ __forceinline__ float bfhi(u32 u){ return __uint_as_float(u & 0xffff0000u); }
__device__ __forceinline__ float bf2f(u16 s){ return __uint_as_float(((u32)s)<<16); }
__device__ __forceinline__ u16 f2bf(float f){
  u32 u = __float_as_uint(f);
  u += 0x7fffu + ((u>>16)&1u);
  return (u16)(u>>16);
}
__device__ __forceinline__ floatx4 mfma16(short8 a, short8 b, floatx4 c){
  return __builtin_amdgcn_mfma_f32_16x16x32_bf16(
      __builtin_bit_cast(bf16x8, a), __builtin_bit_cast(bf16x8, b), c, 0, 0, 0);
}

// ---------------- fp32 -> bf16 conversion (4 elems/thread) ----------------
__global__ __launch_bounds__(256) void k_cvt(
    const float* __restrict__ in, u16* __restrict__ outb, int n4)
{
  int i = blockIdx.x*256 + threadIdx.x;
  if (i >= n4) return;
  float4 v = ((const float4*)in)[i];
  uint2 o;
  o.x = (u32)f2bf(v.x) | ((u32)f2bf(v.y) << 16);
  o.y = (u32)f2bf(v.z) | ((u32)f2bf(v.w) << 16);
  ((uint2*)outb)[i] = o;
}

// ---------------- rmsnorm1 + rope (per token), fp32 in -> bf16 out ----------------
__global__ __launch_bounds__(256) void k_rmsnorm_rope(
    const float* __restrict__ x, const float* __restrict__ w, u16* __restrict__ xr)
{
  int tok = blockIdx.x;
  int s = tok & (SEQ-1);
  int tid = threadIdx.x;
  const float* xrow = x + (size_t)tok * D_MODEL;
  __shared__ float red[256];
  float4 v = ((const float4*)xrow)[tid];
  red[tid] = v.x*v.x + v.y*v.y + v.z*v.z + v.w*v.w;
  __syncthreads();
  for (int o=128;o>0;o>>=1){ if(tid<o) red[tid]+=red[tid+o]; __syncthreads(); }
  float inv = rsqrtf(red[0]*(1.0f/D_MODEL) + 1e-6f);
  u16* orow = xr + (size_t)tok * D_MODEL;
  #pragma unroll
  for (int ii=0; ii<2; ii++){
    int i = tid + ii*256;                 // pair index 0..511
    float2 p = ((const float2*)xrow)[i];
    float2 wp = ((const float2*)w)[i];
    float xe = p.x*inv*wp.x;
    float xo = p.y*inv*wp.y;
    float th = __expf(-(float)i * (9.210340371976184f/512.0f));  // 10000^(-i/512)
    float ang = (float)s * th;
    float c = cosf(ang), sn = sinf(ang);
    orow[i]       = f2bf(xe*c - xo*sn);
    orow[i+512]   = f2bf(xe*sn + xo*c);
  }
}

// ---------------- generic bf16 GEMM: C[MxN] = A[MxK] @ B[KxN], bf16 out ----------------
__global__ __launch_bounds__(256) void k_gemm(
    const u16* __restrict__ A, const u16* __restrict__ B,
    u16* __restrict__ C, int M, int N, int K)
{
  __shared__ u16 As[64*32];
  __shared__ u16 Bs[32*BPAD];
  int tid = threadIdx.x;
  int m0 = blockIdx.y*64, n0 = blockIdx.x*64;
  int wave = tid>>6, lane = tid&63, l15 = lane&15, q = lane>>4;
  int ar = tid>>2, ac = (tid&3)*8;
  int bkr = tid>>3, bnc = (tid&7)*8;
  floatx4 acc[4];
  #pragma unroll
  for (int t=0;t<4;t++) acc[t] = (floatx4){0.f,0.f,0.f,0.f};
  for (int k0=0;k0<K;k0+=32){
    __syncthreads();
    uint4 av = *(const uint4*)(A + (size_t)(m0+ar)*K + k0 + ac);
    *(uint4*)&As[ar*32+ac] = av;
    uint4 bv = *(const uint4*)(B + (size_t)(k0+bkr)*N + n0 + bnc);
    u32* bw = (u32*)&Bs[bkr*BPAD + bnc];
    bw[0]=bv.x; bw[1]=bv.y; bw[2]=bv.z; bw[3]=bv.w;
    __syncthreads();
    short8 af = *(const short8*)&As[(wave*16 + l15)*32 + q*8];
    #pragma unroll
    for (int t=0;t<4;t++){
      short8 bf;
      #pragma unroll
      for (int j=0;j<8;j++) bf[j] = (short)Bs[(q*8+j)*BPAD + t*16 + l15];
      acc[t] = mfma16(af, bf, acc[t]);
    }
  }
  #pragma unroll
  for (int t=0;t<4;t++){
    #pragma unroll
    for (int r=0;r<4;r++){
      int row = m0 + wave*16 + q*4 + r;     // C/D: row=(lane>>4)*4+reg, col=lane&15
      int col = n0 + t*16 + l15;
      C[(size_t)row*N + col] = f2bf(acc[t][r]);
    }
  }
}

// ---------------- GEMM + fp32 residual -> fp32 out (h = x + attn@Wo) ----------------
__global__ __launch_bounds__(256) void k_gemm_resid(
    const u16* __restrict__ A, const u16* __restrict__ B,
    const float* __restrict__ resid, float* __restrict__ Cacc, int M, int N, int K)
{
  __shared__ u16 As[64*32];
  __shared__ u16 Bs[32*BPAD];
  int tid = threadIdx.x;
  int m0 = blockIdx.y*64, n0 = blockIdx.x*64;
  int wave = tid>>6, lane = tid&63, l15 = lane&15, q = lane>>4;
  int ar = tid>>2, ac = (tid&3)*8;
  int bkr = tid>>3, bnc = (tid&7)*8;
  floatx4 acc[4];
  #pragma unroll
  for (int t=0;t<4;t++) acc[t] = (floatx4){0.f,0.f,0.f,0.f};
  for (int k0=0;k0<K;k0+=32){
    __syncthreads();
    uint4 av = *(const uint4*)(A + (size_t)(m0+ar)*K + k0 + ac);
    *(uint4*)&As[ar*32+ac] = av;
    uint4 bv = *(const uint4*)(B + (size_t)(k0+bkr)*N + n0 + bnc);
    u32* bw = (u32*)&Bs[bkr*BPAD + bnc];
    bw[0]=bv.x; bw[1]=bv.y; bw[2]=bv.z; bw[3]=bv.w;
    __syncthreads();
    short8 af = *(const short8*)&As[(wave*16 + l15)*32 + q*8];
    #pragma unroll
    for (int t=0;t<4;t++){
      short8 bf;
      #pragma unroll
      for (int j=0;j<8;j++) bf[j] = (short)Bs[(q*8+j)*BPAD + t*16 + l15];
      acc[t] = mfma16(af, bf, acc[t]);
    }
  }
  #pragma unroll
  for (int t=0;t<4;t++){
    #pragma unroll
    for (int r=0;r<4;r++){
      int row = m0 + wave*16 + q*4 + r;
      int col = n0 + t*16 + l15;
      Cacc[(size_t)row*N + col] = acc[t][r] + resid[(size_t)row*N + col];
    }
  }
}

// ---------------- attention: one block per (b,h,s) query row, two-pass softmax ----------------
__global__ __launch_bounds__(256) void k_attn(
    const u16* __restrict__ Q, const u16* __restrict__ Kb,
    const u16* __restrict__ V, u16* __restrict__ O)
{
  int bidx = blockIdx.x;
  int s = bidx & (SEQ-1);
  int h = (bidx >> 10) & (N_HEADS-1);
  int b = bidx >> 14;
  int g = h >> 2;
  int tid = threadIdx.x;
  __shared__ float qs[64];
  __shared__ float sc[SEQ];
  __shared__ float red[256];
  __shared__ float part[256];
  const u16* qrow = Q + ((size_t)(b*SEQ+s))*D_MODEL + h*64;
  if (tid < 64) qs[tid] = bf2f(qrow[tid]) * 0.125f;   // 1/sqrt(64)
  __syncthreads();
  float lmax = -1e30f;
  for (int t = tid; t <= s; t += 256){
    const uint4* kp = (const uint4*)(Kb + ((size_t)(b*SEQ+t))*KVD + g*64);
    float dot = 0.f;
    #pragma unroll
    for (int i=0;i<8;i++){
      uint4 kv = kp[i];
      dot += qs[i*8+0]*bflo(kv.x) + qs[i*8+1]*bfhi(kv.x)
           + qs[i*8+2]*bflo(kv.y) + qs[i*8+3]*bfhi(kv.y)
           + qs[i*8+4]*bflo(kv.z) + qs[i*8+5]*bfhi(kv.z)
           + qs[i*8+6]*bflo(kv.w) + qs[i*8+7]*bfhi(kv.w);
    }
    sc[t] = dot;
    lmax = fmaxf(lmax, dot);
  }
  red[tid] = lmax; __syncthreads();
  for (int o=128;o>0;o>>=1){ if(tid<o) red[tid]=fmaxf(red[tid],red[tid+o]); __syncthreads(); }
  float m = red[0];
  __syncthreads();
  float lsum = 0.f;
  for (int t = tid; t <= s; t += 256){
    float p = __expf(sc[t]-m);
    sc[t] = p; lsum += p;
  }
  red[tid] = lsum; __syncthreads();
  for (int o=128;o>0;o>>=1){ if(tid<o) red[tid]+=red[tid+o]; __syncthreads(); }
  float linv = 1.0f / red[0];
  int c = tid >> 6, d = tid & 63;
  float o = 0.f;
  for (int t = c; t <= s; t += 4)
    o += sc[t] * bf2f(V[((size_t)(b*SEQ+t))*KVD + g*64 + d]);
  part[tid] = o; __syncthreads();
  if (tid < 64){
    float r = (part[tid]+part[64+tid]+part[128+tid]+part[192+tid])*linv;
    O[((size_t)(b*SEQ+s))*D_MODEL + h*64 + tid] = f2bf(r);
  }
}

// ---------------- rmsnorm2 (fp32 in, bf16 out) ----------------
__global__ __launch_bounds__(256) void k_rmsnorm2(
    const float* __restrict__ hacc, const float* __restrict__ w, u16* __restrict__ hn)
{
  int tok = blockIdx.x, tid = threadIdx.x;
  float4 v = ((const float4*)(hacc + (size_t)tok*D_MODEL))[tid];
  __shared__ float red[256];
  red[tid] = v.x*v.x + v.y*v.y + v.z*v.z + v.w*v.w;
  __syncthreads();
  for (int o=128;o>0;o>>=1){ if(tid<o) red[tid]+=red[tid+o]; __syncthreads(); }
  float inv = rsqrtf(red[0]*(1.0f/D_MODEL) + 1e-6f);
  int i = tid*4;
  float4 wv = ((const float4*)w)[tid];
  u16* orow = hn + (size_t)tok*D_MODEL;
  orow[i+0] = f2bf(v.x*inv*wv.x);
  orow[i+1] = f2bf(v.y*inv*wv.y);
  orow[i+2] = f2bf(v.z*inv*wv.z);
  orow[i+3] = f2bf(v.w*inv*wv.w);
}

// ---------------- router: one wave per token, FULL FP32 (norm + logits + top-2) ----------------
// Router decisions are discrete; computing from bf16-rounded activations flips
// near-tie expert choices vs the fp32 numpy reference (observed absmax 0.65).
__global__ __launch_bounds__(64) void k_router(
    const float* __restrict__ hacc, const float* __restrict__ w2,
    const float* __restrict__ rw, const float* __restrict__ rb,
    int* __restrict__ topi, float* __restrict__ topw)
{
  int tok = blockIdx.x, lane = threadIdx.x;
  const float* xrow = hacc + (size_t)tok*D_MODEL;
  float ss = 0.f;
  #pragma unroll
  for (int ii=0; ii<4; ii++){
    float4 v = ((const float4*)xrow)[lane + ii*64];
    ss += v.x*v.x + v.y*v.y + v.z*v.z + v.w*v.w;
  }
  #pragma unroll
  for (int o=32;o>0;o>>=1) ss += __shfl_down(ss, o, 64);
  ss = __shfl(ss, 0, 64);
  float inv = rsqrtf(ss*(1.0f/D_MODEL) + 1e-6f);
  float accv[8] = {0.f,0.f,0.f,0.f,0.f,0.f,0.f,0.f};
  for (int d = lane; d < D_MODEL; d += 64){
    float xv = xrow[d]*inv*w2[d];
    float4 r0 = ((const float4*)(rw + (size_t)d*8))[0];
    float4 r1 = ((const float4*)(rw + (size_t)d*8))[1];
    accv[0] += xv*r0.x; accv[1] += xv*r0.y;
    accv[2] += xv*r0.z; accv[3] += xv*r0.w;
    accv[4] += xv*r1.x; accv[5] += xv*r1.y;
    accv[6] += xv*r1.z; accv[7] += xv*r1.w;
  }
  #pragma unroll
  for (int e=0;e<8;e++){
    #pragma unroll
    for (int o=32;o>0;o>>=1) accv[e] += __shfl_down(accv[e], o, 64);
  }
  if (lane==0){
    float lg[8];
    #pragma unroll
    for (int e=0;e<8;e++) lg[e] = accv[e] + rb[e];
    int i0=0; float v0=lg[0];
    for (int e=1;e<8;e++) if (lg[e]>v0){v0=lg[e]; i0=e;}
    int i1=-1; float v1=-1e30f;
    for (int e=0;e<8;e++) if (e!=i0 && lg[e]>v1){v1=lg[e]; i1=e;}
    float e1 = __expf(v1-v0);
    float wsum = 1.f + e1;
    topi[tok*2+0]=i0; topi[tok*2+1]=i1;
    topw[tok*2+0]=1.f/wsum; topw[tok*2+1]=e1/wsum;
  }
}

// ---------------- pack: per-expert packed token lists (single block) ----------------
__global__ __launch_bounds__(256) void k_pack(
    const int* __restrict__ topi, const float* __restrict__ topw,
    int* __restrict__ off, int* __restrict__ perm, float* __restrict__ pw)
{
  __shared__ int cnt[8], cur[8], offs[9];
  int tid = threadIdx.x;
  if (tid<8) cnt[tid]=0;
  __syncthreads();
  for (int i=tid;i<NTOK*2;i+=256) atomicAdd(&cnt[topi[i]],1);
  __syncthreads();
  if (tid==0){
    int s=0;
    for (int e=0;e<8;e++){ offs[e]=s; s+=cnt[e]; }
    offs[8]=s;
    for (int e=0;e<9;e++) off[e]=offs[e];
  }
  __syncthreads();
  if (tid<8) cur[tid]=offs[tid];
  __syncthreads();
  for (int i=tid;i<NTOK*2;i+=256){
    int e = topi[i];
    int pos = atomicAdd(&cur[e],1);
    perm[pos] = i>>1;
    pw[pos]   = topw[i];
  }
}

// ---------------- MoE stage1: H = silu(Xg@W1+b1) * (Xg@W2+b2), gathered rows ----------------
__global__ __launch_bounds__(256) void k_moe1(
    const u16* __restrict__ hn,
    const u16* __restrict__ W1, const float* __restrict__ b1,
    const u16* __restrict__ W2, const float* __restrict__ b2,
    const int* __restrict__ off, const int* __restrict__ perm,
    u16* __restrict__ H)
{
  int e = blockIdx.z;
  int base = off[e], cnte = off[e+1]-off[e];
  int mt = blockIdx.y;
  if (mt*64 >= cnte) return;
  int n0 = blockIdx.x*64;
  __shared__ u16 As[64*32];
  __shared__ u16 B1s[32*BPAD];
  __shared__ u16 B2s[32*BPAD];
  __shared__ int toks[64];
  int tid = threadIdx.x;
  int wave = tid>>6, lane = tid&63, l15 = lane&15, q = lane>>4;
  int ar = tid>>2, ac = (tid&3)*8;
  int bkr = tid>>3, bnc = (tid&7)*8;
  if (tid < 64){
    int r = mt*64 + tid;
    toks[tid] = (r < cnte) ? perm[base+r] : -1;
  }
  const u16* B1 = W1 + (size_t)e*D_MODEL*D_FF;
  const u16* B2 = W2 + (size_t)e*D_MODEL*D_FF;
  floatx4 acc1[4], acc2[4];
  #pragma unroll
  for (int t=0;t<4;t++){ acc1[t]=(floatx4){0.f,0.f,0.f,0.f}; acc2[t]=(floatx4){0.f,0.f,0.f,0.f}; }
  __syncthreads();
  for (int k0=0;k0<D_MODEL;k0+=32){
    __syncthreads();
    int t = toks[ar];
    uint4 av = {0,0,0,0};
    if (t >= 0) av = *(const uint4*)(hn + (size_t)t*D_MODEL + k0 + ac);
    *(uint4*)&As[ar*32+ac] = av;
    uint4 b1v = *(const uint4*)(B1 + (size_t)(k0+bkr)*D_FF + n0 + bnc);
    uint4 b2v = *(const uint4*)(B2 + (size_t)(k0+bkr)*D_FF + n0 + bnc);
    u32* w1p = (u32*)&B1s[bkr*BPAD + bnc];
    w1p[0]=b1v.x; w1p[1]=b1v.y; w1p[2]=b1v.z; w1p[3]=b1v.w;
    u32* w2p = (u32*)&B2s[bkr*BPAD + bnc];
    w2p[0]=b2v.x; w2p[1]=b2v.y; w2p[2]=b2v.z; w2p[3]=b2v.w;
    __syncthreads();
    short8 af = *(const short8*)&As[(wave*16 + l15)*32 + q*8];
    #pragma unroll
    for (int tt=0;tt<4;tt++){
      short8 bf1, bf2;
      #pragma unroll
      for (int j=0;j<8;j++){
        bf1[j] = (short)B1s[(q*8+j)*BPAD + tt*16 + l15];
        bf2[j] = (short)B2s[(q*8+j)*BPAD + tt*16 + l15];
      }
      acc1[tt] = mfma16(af, bf1, acc1[tt]);
      acc2[tt] = mfma16(af, bf2, acc2[tt]);
    }
  }
  #pragma unroll
  for (int tt=0;tt<4;tt++){
    #pragma unroll
    for (int r=0;r<4;r++){
      int rloc = wave*16 + q*4 + r;
      if (mt*64 + rloc < cnte){
        int col = n0 + tt*16 + l15;
        float h1 = acc1[tt][r] + b1[e*D_FF+col];
        float h2 = acc2[tt][r] + b2[e*D_FF+col];
        float sil = h1 / (1.f + __expf(-h1));
        H[(size_t)(base + mt*64 + rloc)*D_FF + col] = f2bf(h2*sil);
      }
    }
  }
}

// ---------------- MoE stage2: acc[token] += w * (H@W3 + b3) ----------------
__global__ __launch_bounds__(256) void k_moe2(
    const u16* __restrict__ H, const u16* __restrict__ W3, const float* __restrict__ b3,
    const int* __restrict__ off, const int* __restrict__ perm, const float* __restrict__ pw,
    float* __restrict__ accb)
{
  int e = blockIdx.z;
  int base = off[e], cnte = off[e+1]-off[e];
  int mt = blockIdx.y;
  if (mt*64 >= cnte) return;
  int n0 = blockIdx.x*64;
  __shared__ u16 As[64*32];
  __shared__ u16 Bs[32*BPAD];
  int tid = threadIdx.x;
  int wave = tid>>6, lane = tid&63, l15 = lane&15, q = lane>>4;
  int ar = tid>>2, ac = (tid&3)*8;
  int bkr = tid>>3, bnc = (tid&7)*8;
  const u16* B = W3 + (size_t)e*D_FF*D_MODEL;
  floatx4 acc[4];
  #pragma unroll
  for (int t=0;t<4;t++) acc[t] = (floatx4){0.f,0.f,0.f,0.f};
  for (int k0=0;k0<D_FF;k0+=32){
    __syncthreads();
    int grow = mt*64 + ar;
    uint4 av = {0,0,0,0};
    if (grow < cnte) av = *(const uint4*)(H + (size_t)(base+grow)*D_FF + k0 + ac);
    *(uint4*)&As[ar*32+ac] = av;
    uint4 bv = *(const uint4*)(B + (size_t)(k0+bkr)*D_MODEL + n0 + bnc);
    u32* bw = (u32*)&Bs[bkr*BPAD + bnc];
    bw[0]=bv.x; bw[1]=bv.y; bw[2]=bv.z; bw[3]=bv.w;
    __syncthreads();
    short8 af = *(const short8*)&As[(wave*16 + l15)*32 + q*8];
    #pragma unroll
    for (int t=0;t<4;t++){
      short8 bf;
      #pragma unroll
      for (int j=0;j<8;j++) bf[j] = (short)Bs[(q*8+j)*BPAD + t*16 + l15];
      acc[t] = mfma16(af, bf, acc[t]);
    }
  }
  #pragma unroll
  for (int t=0;t<4;t++){
    #pragma unroll
    for (int r=0;r<4;r++){
      int rloc = wave*16 + q*4 + r;
      int grow = mt*64 + rloc;
      if (grow < cnte){
        int col = n0 + t*16 + l15;
        int tok = perm[base+grow];
        float wgt = pw[base+grow];
        float val = acc[t][r] + b3[e*D_MODEL+col];
        atomicAdd(accb + (size_t)tok*D_MODEL + col, wgt*val);
      }
    }
  }
}

// ---------------- finalize: out = fp32 acc ----------------
__global__ __launch_bounds__(256) void k_final(const float* __restrict__ accb, float* __restrict__ out)
{
  int i = blockIdx.x*256 + threadIdx.x;       // 4 elems per thread
  ((float4*)out)[i] = ((const float4*)accb)[i];
}

extern "C" void kernel_launch(void* const* d_in, const int* in_sizes, int n_in,
                              void* d_out, int out_size, void* d_ws, size_t ws_size,
                              hipStream_t stream)
{
  const float* x   = (const float*)d_in[0];
  const float* n1w = (const float*)d_in[1];
  const float* Wq  = (const float*)d_in[2];
  const float* Wk  = (const float*)d_in[3];
  const float* Wv  = (const float*)d_in[4];
  const float* Wo  = (const float*)d_in[5];
  const float* n2w = (const float*)d_in[6];
  const float* rw  = (const float*)d_in[7];
  const float* rb  = (const float*)d_in[8];
  const float* W1  = (const float*)d_in[9];
  const float* b1  = (const float*)d_in[10];
  const float* W2  = (const float*)d_in[11];
  const float* b2  = (const float*)d_in[12];
  const float* W3  = (const float*)d_in[13];
  const float* b3  = (const float*)d_in[14];
  float* out = (float*)d_out;

  char* p = (char*)d_ws;
  auto alloc = [&](size_t bytes)->char*{
    char* r = p; p += (bytes + 255) & ~(size_t)255; return r;
  };
  u16*   xr   = (u16*)  alloc((size_t)NTOK*D_MODEL*2);
  u16*   Qb   = (u16*)  alloc((size_t)NTOK*D_MODEL*2);
  u16*   Kb   = (u16*)  alloc((size_t)NTOK*KVD*2);
  u16*   Vb   = (u16*)  alloc((size_t)NTOK*KVD*2);
  u16*   attn = (u16*)  alloc((size_t)NTOK*D_MODEL*2);
  u16*   hn   = (u16*)  alloc((size_t)NTOK*D_MODEL*2);
  float* acc  = (float*)alloc((size_t)NTOK*D_MODEL*4);
  int*   topi = (int*)  alloc((size_t)NTOK*2*4);
  float* topw = (float*)alloc((size_t)NTOK*2*4);
  int*   off  = (int*)  alloc(64);
  int*   perm = (int*)  alloc((size_t)NTOK*2*4);
  float* pw   = (float*)alloc((size_t)NTOK*2*4);
  u16*   H    = (u16*)  alloc((size_t)NTOK*2*D_FF*2);
  // bf16 weight copies
  u16*   Wqb  = (u16*)  alloc((size_t)D_MODEL*D_MODEL*2);
  u16*   Wkb  = (u16*)  alloc((size_t)D_MODEL*KVD*2);
  u16*   Wvb  = (u16*)  alloc((size_t)D_MODEL*KVD*2);
  u16*   Wob  = (u16*)  alloc((size_t)D_MODEL*D_MODEL*2);
  u16*   W1b  = (u16*)  alloc((size_t)N_EXPERTS*D_MODEL*D_FF*2);
  u16*   W2b  = (u16*)  alloc((size_t)N_EXPERTS*D_MODEL*D_FF*2);
  u16*   W3b  = (u16*)  alloc((size_t)N_EXPERTS*D_FF*D_MODEL*2);

  auto cvt = [&](const float* src, u16* dst, size_t n){
    int n4 = (int)(n/4);
    k_cvt<<<(n4+255)/256, 256, 0, stream>>>(src, dst, n4);
  };
  // 0. weight conversion fp32 -> bf16
  cvt(Wq, Wqb, (size_t)D_MODEL*D_MODEL);
  cvt(Wk, Wkb, (size_t)D_MODEL*KVD);
  cvt(Wv, Wvb, (size_t)D_MODEL*KVD);
  cvt(Wo, Wob, (size_t)D_MODEL*D_MODEL);
  cvt(W1, W1b, (size_t)N_EXPERTS*D_MODEL*D_FF);
  cvt(W2, W2b, (size_t)N_EXPERTS*D_MODEL*D_FF);
  cvt(W3, W3b, (size_t)N_EXPERTS*D_FF*D_MODEL);

  // 1. norm1 + rope
  k_rmsnorm_rope<<<NTOK, 256, 0, stream>>>(x, n1w, xr);
  // 2. Q,K,V projections
  k_gemm<<<dim3(D_MODEL/64, NTOK/64), 256, 0, stream>>>(xr, Wqb, Qb, NTOK, D_MODEL, D_MODEL);
  k_gemm<<<dim3(KVD/64,     NTOK/64), 256, 0, stream>>>(xr, Wkb, Kb, NTOK, KVD, D_MODEL);
  k_gemm<<<dim3(KVD/64,     NTOK/64), 256, 0, stream>>>(xr, Wvb, Vb, NTOK, KVD, D_MODEL);
  // 3. attention
  k_attn<<<BATCH*N_HEADS*SEQ, 256, 0, stream>>>(Qb, Kb, Vb, attn);
  // 4. out proj + residual -> h (fp32)
  k_gemm_resid<<<dim3(D_MODEL/64, NTOK/64), 256, 0, stream>>>(attn, Wob, x, acc, NTOK, D_MODEL, D_MODEL);
  // 5. norm2 (bf16 activations for expert GEMMs)
  k_rmsnorm2<<<NTOK, 256, 0, stream>>>(acc, n2w, hn);
  // 6. router (fp32, from fp32 residual) + pack
  k_router<<<NTOK, 64, 0, stream>>>(acc, n2w, rw, rb, topi, topw);
  k_pack<<<1, 256, 0, stream>>>(topi, topw, off, perm, pw);
  // 7. expert FFN
  k_moe1<<<dim3(D_FF/64, 32, N_EXPERTS), 256, 0, stream>>>(hn, W1b, b1, W2b, b2, off, perm, H);
  k_moe2<<<dim3(D_MODEL/64, 32, N_EXPERTS), 256, 0, stream>>>(H, W3b, b3, off, perm, pw, acc);
  // 8. finalize
  k_final<<<(NTOK*D_MODEL/4)/256, 256, 0, stream>>>(acc, out);
}

// Round 4
// 1107.235 us; speedup vs baseline: 1.5524x; 1.5524x over previous
//
#include <hip/hip_runtime.h>

#define D_MODEL 1024
#define N_HEADS 16
#define N_GROUPS 4
#define D_FF 4096
#define N_EXPERTS 8
#define BATCH 2
#define SEQ 1024
#define DK 64
#define NTOK (BATCH*SEQ)
#define KVD (N_GROUPS*DK)
#define BPAD 66   // 32xBPAD LDS B tile: +2 pad spreads k-rows across banks for scalar frag reads
#define APAD 72   // attention LDS row stride (64+8): 16B-aligned, rotates banks across rows

typedef unsigned short u16;
typedef unsigned int u32;
typedef __attribute__((ext_vector_type(8))) short short8;
typedef __attribute__((ext_vector_type(8))) __bf16 bf16x8;
typedef __attribute__((ext_vector_type(4))) float floatx4;

__device__ __forceinline__ float bflo(u32 u){ return __uint_as_float(u<<16); }
__device__ __forceinline__ float bfhi(u32 u){ return __uint_as_float(u & 0xffff0000u); }
__device__ __forceinline__ float bf2f(u16 s){ return __uint_as_float(((u32)s)<<16); }
__device__ __forceinline__ u16 f2bf(float f){
  u32 u = __float_as_uint(f);
  u += 0x7fffu + ((u>>16)&1u);
  return (u16)(u>>16);
}
__device__ __forceinline__ floatx4 mfma16(short8 a, short8 b, floatx4 c){
  return __builtin_amdgcn_mfma_f32_16x16x32_bf16(
      __builtin_bit_cast(bf16x8, a), __builtin_bit_cast(bf16x8, b), c, 0, 0, 0);
}

// ---------------- fp32 -> bf16 conversion (4 elems/thread) ----------------
__global__ __launch_bounds__(256) void k_cvt(
    const float* __restrict__ in, u16* __restrict__ outb, int n4)
{
  int i = blockIdx.x*256 + threadIdx.x;
  if (i >= n4) return;
  float4 v = ((const float4*)in)[i];
  uint2 o;
  o.x = (u32)f2bf(v.x) | ((u32)f2bf(v.y) << 16);
  o.y = (u32)f2bf(v.z) | ((u32)f2bf(v.w) << 16);
  ((uint2*)outb)[i] = o;
}

// ---------------- rmsnorm1 + rope (per token), fp32 in -> bf16 out ----------------
__global__ __launch_bounds__(256) void k_rmsnorm_rope(
    const float* __restrict__ x, const float* __restrict__ w, u16* __restrict__ xr)
{
  int tok = blockIdx.x;
  int s = tok & (SEQ-1);
  int tid = threadIdx.x;
  const float* xrow = x + (size_t)tok * D_MODEL;
  __shared__ float red[256];
  float4 v = ((const float4*)xrow)[tid];
  red[tid] = v.x*v.x + v.y*v.y + v.z*v.z + v.w*v.w;
  __syncthreads();
  for (int o=128;o>0;o>>=1){ if(tid<o) red[tid]+=red[tid+o]; __syncthreads(); }
  float inv = rsqrtf(red[0]*(1.0f/D_MODEL) + 1e-6f);
  u16* orow = xr + (size_t)tok * D_MODEL;
  #pragma unroll
  for (int ii=0; ii<2; ii++){
    int i = tid + ii*256;                 // pair index 0..511
    float2 p = ((const float2*)xrow)[i];
    float2 wp = ((const float2*)w)[i];
    float xe = p.x*inv*wp.x;
    float xo = p.y*inv*wp.y;
    float th = __expf(-(float)i * (9.210340371976184f/512.0f));  // 10000^(-i/512)
    float ang = (float)s * th;
    float c = cosf(ang), sn = sinf(ang);
    orow[i]       = f2bf(xe*c - xo*sn);
    orow[i+512]   = f2bf(xe*sn + xo*c);
  }
}

// ---------------- generic bf16 GEMM: C[MxN] = A[MxK] @ B[KxN], bf16 out ----------------
__global__ __launch_bounds__(256) void k_gemm(
    const u16* __restrict__ A, const u16* __restrict__ B,
    u16* __restrict__ C, int M, int N, int K)
{
  __shared__ u16 As[64*32];
  __shared__ u16 Bs[32*BPAD];
  int tid = threadIdx.x;
  int m0 = blockIdx.y*64, n0 = blockIdx.x*64;
  int wave = tid>>6, lane = tid&63, l15 = lane&15, q = lane>>4;
  int ar = tid>>2, ac = (tid&3)*8;
  int bkr = tid>>3, bnc = (tid&7)*8;
  floatx4 acc[4];
  #pragma unroll
  for (int t=0;t<4;t++) acc[t] = (floatx4){0.f,0.f,0.f,0.f};
  for (int k0=0;k0<K;k0+=32){
    __syncthreads();
    uint4 av = *(const uint4*)(A + (size_t)(m0+ar)*K + k0 + ac);
    *(uint4*)&As[ar*32+ac] = av;
    uint4 bv = *(const uint4*)(B + (size_t)(k0+bkr)*N + n0 + bnc);
    u32* bw = (u32*)&Bs[bkr*BPAD + bnc];
    bw[0]=bv.x; bw[1]=bv.y; bw[2]=bv.z; bw[3]=bv.w;
    __syncthreads();
    short8 af = *(const short8*)&As[(wave*16 + l15)*32 + q*8];
    #pragma unroll
    for (int t=0;t<4;t++){
      short8 bf;
      #pragma unroll
      for (int j=0;j<8;j++) bf[j] = (short)Bs[(q*8+j)*BPAD + t*16 + l15];
      acc[t] = mfma16(af, bf, acc[t]);
    }
  }
  #pragma unroll
  for (int t=0;t<4;t++){
    #pragma unroll
    for (int r=0;r<4;r++){
      int row = m0 + wave*16 + q*4 + r;     // C/D: row=(lane>>4)*4+reg, col=lane&15
      int col = n0 + t*16 + l15;
      C[(size_t)row*N + col] = f2bf(acc[t][r]);
    }
  }
}

// ---------------- GEMM + fp32 residual -> fp32 out (h = x + attn@Wo) ----------------
__global__ __launch_bounds__(256) void k_gemm_resid(
    const u16* __restrict__ A, const u16* __restrict__ B,
    const float* __restrict__ resid, float* __restrict__ Cacc, int M, int N, int K)
{
  __shared__ u16 As[64*32];
  __shared__ u16 Bs[32*BPAD];
  int tid = threadIdx.x;
  int m0 = blockIdx.y*64, n0 = blockIdx.x*64;
  int wave = tid>>6, lane = tid&63, l15 = lane&15, q = lane>>4;
  int ar = tid>>2, ac = (tid&3)*8;
  int bkr = tid>>3, bnc = (tid&7)*8;
  floatx4 acc[4];
  #pragma unroll
  for (int t=0;t<4;t++) acc[t] = (floatx4){0.f,0.f,0.f,0.f};
  for (int k0=0;k0<K;k0+=32){
    __syncthreads();
    uint4 av = *(const uint4*)(A + (size_t)(m0+ar)*K + k0 + ac);
    *(uint4*)&As[ar*32+ac] = av;
    uint4 bv = *(const uint4*)(B + (size_t)(k0+bkr)*N + n0 + bnc);
    u32* bw = (u32*)&Bs[bkr*BPAD + bnc];
    bw[0]=bv.x; bw[1]=bv.y; bw[2]=bv.z; bw[3]=bv.w;
    __syncthreads();
    short8 af = *(const short8*)&As[(wave*16 + l15)*32 + q*8];
    #pragma unroll
    for (int t=0;t<4;t++){
      short8 bf;
      #pragma unroll
      for (int j=0;j<8;j++) bf[j] = (short)Bs[(q*8+j)*BPAD + t*16 + l15];
      acc[t] = mfma16(af, bf, acc[t]);
    }
  }
  #pragma unroll
  for (int t=0;t<4;t++){
    #pragma unroll
    for (int r=0;r<4;r++){
      int row = m0 + wave*16 + q*4 + r;
      int col = n0 + t*16 + l15;
      Cacc[(size_t)row*N + col] = acc[t][r] + resid[(size_t)row*N + col];
    }
  }
}

// ---------------- V transpose: Vb[tok][KVD] -> Vt[b][g][d][s] (LDS-tiled) ----------------
__global__ __launch_bounds__(256) void k_vtrans(
    const u16* __restrict__ Vb, u16* __restrict__ Vt)
{
  int st = blockIdx.x;          // s-tile (SEQ/64)
  int bg = blockIdx.y;          // b*4+g
  int b = bg >> 2, g = bg & 3;
  int tid = threadIdx.x;
  __shared__ u16 tile[64*APAD];
  #pragma unroll
  for (int i=0;i<2;i++){
    int idx = i*256 + tid;
    int srow = idx >> 3, cch = (idx&7)*8;
    uint4 v = *(const uint4*)(Vb + ((size_t)(b*SEQ + st*64 + srow))*KVD + g*64 + cch);
    *(uint4*)&tile[srow*APAD + cch] = v;
  }
  __syncthreads();
  #pragma unroll
  for (int i=0;i<2;i++){
    int idx = i*256 + tid;
    int drow = idx >> 3, sch = (idx&7)*8;
    u16 tmp[8];
    #pragma unroll
    for (int j=0;j<8;j++) tmp[j] = tile[(sch+j)*APAD + drow];
    *(uint4*)(Vt + ((size_t)(bg*64 + drow))*SEQ + st*64 + sch) = *(uint4*)tmp;
  }
}

// ---------------- flash attention: 64-row Q-tile per block, MFMA QK^T & PV ----------------
// grid (S/64, H, B), 256 thr = 4 waves, each wave owns 16 query rows.
__global__ __launch_bounds__(256) void k_attn_flash(
    const u16* __restrict__ Q, const u16* __restrict__ Kb,
    const u16* __restrict__ Vt, u16* __restrict__ O)
{
  int qt = blockIdx.x, h = blockIdx.y, b = blockIdx.z;
  int g = h >> 2;
  int tid = threadIdx.x, wave = tid>>6, lane = tid&63, l15 = lane&15, q = lane>>4;
  __shared__ u16 Ks[64*APAD];
  __shared__ u16 Vs[64*APAD];        // transposed V tile: [d][key]
  __shared__ u16 Ps[4*16*APAD];      // per-wave P buffer (C-layout -> A-layout round trip)

  int qbase = qt*64;
  // Q A-fragments (A[m=lane&15][k=q*8+j]), rows qbase+wave*16+l15, head slice h*64
  const u16* qrow = Q + ((size_t)(b*SEQ + qbase + wave*16 + l15))*D_MODEL + h*64;
  short8 qa0 = *(const short8*)(qrow + q*8);
  short8 qa1 = *(const short8*)(qrow + 32 + q*8);

  floatx4 Of[4];
  #pragma unroll
  for (int nt=0;nt<4;nt++) Of[nt] = (floatx4){0.f,0.f,0.f,0.f};
  float mrun[4], lrun[4];
  #pragma unroll
  for (int r=0;r<4;r++){ mrun[r] = -1e30f; lrun[r] = 0.f; }

  for (int t=0; t<=qt; ++t){
    int kbase = t*64;
    __syncthreads();   // all waves done reading previous Ks/Vs
    #pragma unroll
    for (int i=0;i<2;i++){
      int idx = i*256 + tid;
      int row = idx >> 3, cch = (idx&7)*8;
      uint4 kv = *(const uint4*)(Kb + ((size_t)(b*SEQ + kbase + row))*KVD + g*64 + cch);
      *(uint4*)&Ks[row*APAD + cch] = kv;
      uint4 vv = *(const uint4*)(Vt + ((size_t)((b*4+g)*64 + row))*SEQ + kbase + cch);
      *(uint4*)&Vs[row*APAD + cch] = vv;
    }
    __syncthreads();

    // S = Q @ K^T  (B-frag of QK^T = K rows, contiguous in d)
    floatx4 Sf[4];
    #pragma unroll
    for (int jt=0;jt<4;jt++){
      short8 bf0 = *(const short8*)&Ks[(jt*16+l15)*APAD + q*8];
      short8 bf1 = *(const short8*)&Ks[(jt*16+l15)*APAD + 32 + q*8];
      Sf[jt] = mfma16(qa0, bf0, (floatx4){0.f,0.f,0.f,0.f});
      Sf[jt] = mfma16(qa1, bf1, Sf[jt]);
    }
    bool maskt = (t == qt);
    // online softmax per output row (row = q*4+r)
    #pragma unroll
    for (int r=0;r<4;r++){
      float s0 = Sf[0][r]*0.125f, s1 = Sf[1][r]*0.125f,
            s2 = Sf[2][r]*0.125f, s3 = Sf[3][r]*0.125f;
      if (maskt){
        int qg = qbase + wave*16 + q*4 + r;
        if (kbase +      l15 > qg) s0 = -1e30f;
        if (kbase + 16 + l15 > qg) s1 = -1e30f;
        if (kbase + 32 + l15 > qg) s2 = -1e30f;
        if (kbase + 48 + l15 > qg) s3 = -1e30f;
      }
      float mx = fmaxf(fmaxf(s0,s1), fmaxf(s2,s3));
      #pragma unroll
      for (int o=1;o<16;o<<=1) mx = fmaxf(mx, __shfl_xor(mx, o, 64));
      float mc = fmaxf(mrun[r], mx);
      float alpha = __expf(mrun[r]-mc);
      float p0 = __expf(s0-mc), p1 = __expf(s1-mc), p2 = __expf(s2-mc), p3 = __expf(s3-mc);
      float rs = p0+p1+p2+p3;
      #pragma unroll
      for (int o=1;o<16;o<<=1) rs += __shfl_xor(rs, o, 64);
      lrun[r] = lrun[r]*alpha + rs;
      mrun[r] = mc;
      #pragma unroll
      for (int nt=0;nt<4;nt++){
        Of[nt][r] *= alpha;
      }
      int prow = wave*16*APAD + (q*4+r)*APAD;
      Ps[prow +      l15] = f2bf(p0);
      Ps[prow + 16 + l15] = f2bf(p1);
      Ps[prow + 32 + l15] = f2bf(p2);
      Ps[prow + 48 + l15] = f2bf(p3);
    }
    // O += P @ V   (P A-frag from per-wave LDS; V^T rows give contiguous B-frags)
    #pragma unroll
    for (int ks=0;ks<2;ks++){
      short8 pa = *(const short8*)&Ps[wave*16*APAD + l15*APAD + ks*32 + q*8];
      #pragma unroll
      for (int nt=0;nt<4;nt++){
        short8 vb = *(const short8*)&Vs[(nt*16+l15)*APAD + ks*32 + q*8];
        Of[nt] = mfma16(pa, vb, Of[nt]);
      }
    }
  }
  // epilogue
  #pragma unroll
  for (int r=0;r<4;r++){
    float linv = 1.0f / lrun[r];
    int row = b*SEQ + qbase + wave*16 + q*4 + r;
    #pragma unroll
    for (int nt=0;nt<4;nt++){
      O[(size_t)row*D_MODEL + h*64 + nt*16 + l15] = f2bf(Of[nt][r]*linv);
    }
  }
}

// ---------------- rmsnorm2 (fp32 in, bf16 out) ----------------
__global__ __launch_bounds__(256) void k_rmsnorm2(
    const float* __restrict__ hacc, const float* __restrict__ w, u16* __restrict__ hn)
{
  int tok = blockIdx.x, tid = threadIdx.x;
  float4 v = ((const float4*)(hacc + (size_t)tok*D_MODEL))[tid];
  __shared__ float red[256];
  red[tid] = v.x*v.x + v.y*v.y + v.z*v.z + v.w*v.w;
  __syncthreads();
  for (int o=128;o>0;o>>=1){ if(tid<o) red[tid]+=red[tid+o]; __syncthreads(); }
  float inv = rsqrtf(red[0]*(1.0f/D_MODEL) + 1e-6f);
  int i = tid*4;
  float4 wv = ((const float4*)w)[tid];
  u16* orow = hn + (size_t)tok*D_MODEL;
  orow[i+0] = f2bf(v.x*inv*wv.x);
  orow[i+1] = f2bf(v.y*inv*wv.y);
  orow[i+2] = f2bf(v.z*inv*wv.z);
  orow[i+3] = f2bf(v.w*inv*wv.w);
}

// ---------------- router: one wave per token, FULL FP32 (norm + logits + top-2) ----------------
// Router decisions are discrete; computing from bf16-rounded activations flips
// near-tie expert choices vs the fp32 numpy reference (observed absmax 0.65).
__global__ __launch_bounds__(64) void k_router(
    const float* __restrict__ hacc, const float* __restrict__ w2,
    const float* __restrict__ rw, const float* __restrict__ rb,
    int* __restrict__ topi, float* __restrict__ topw)
{
  int tok = blockIdx.x, lane = threadIdx.x;
  const float* xrow = hacc + (size_t)tok*D_MODEL;
  float ss = 0.f;
  #pragma unroll
  for (int ii=0; ii<4; ii++){
    float4 v = ((const float4*)xrow)[lane + ii*64];
    ss += v.x*v.x + v.y*v.y + v.z*v.z + v.w*v.w;
  }
  #pragma unroll
  for (int o=32;o>0;o>>=1) ss += __shfl_down(ss, o, 64);
  ss = __shfl(ss, 0, 64);
  float inv = rsqrtf(ss*(1.0f/D_MODEL) + 1e-6f);
  float accv[8] = {0.f,0.f,0.f,0.f,0.f,0.f,0.f,0.f};
  for (int d = lane; d < D_MODEL; d += 64){
    float xv = xrow[d]*inv*w2[d];
    float4 r0 = ((const float4*)(rw + (size_t)d*8))[0];
    float4 r1 = ((const float4*)(rw + (size_t)d*8))[1];
    accv[0] += xv*r0.x; accv[1] += xv*r0.y;
    accv[2] += xv*r0.z; accv[3] += xv*r0.w;
    accv[4] += xv*r1.x; accv[5] += xv*r1.y;
    accv[6] += xv*r1.z; accv[7] += xv*r1.w;
  }
  #pragma unroll
  for (int e=0;e<8;e++){
    #pragma unroll
    for (int o=32;o>0;o>>=1) accv[e] += __shfl_down(accv[e], o, 64);
  }
  if (lane==0){
    float lg[8];
    #pragma unroll
    for (int e=0;e<8;e++) lg[e] = accv[e] + rb[e];
    int i0=0; float v0=lg[0];
    for (int e=1;e<8;e++) if (lg[e]>v0){v0=lg[e]; i0=e;}
    int i1=-1; float v1=-1e30f;
    for (int e=0;e<8;e++) if (e!=i0 && lg[e]>v1){v1=lg[e]; i1=e;}
    float e1 = __expf(v1-v0);
    float wsum = 1.f + e1;
    topi[tok*2+0]=i0; topi[tok*2+1]=i1;
    topw[tok*2+0]=1.f/wsum; topw[tok*2+1]=e1/wsum;
  }
}

// ---------------- pack: per-expert packed token lists (single block) ----------------
__global__ __launch_bounds__(256) void k_pack(
    const int* __restrict__ topi, const float* __restrict__ topw,
    int* __restrict__ off, int* __restrict__ perm, float* __restrict__ pw)
{
  __shared__ int cnt[8], cur[8], offs[9];
  int tid = threadIdx.x;
  if (tid<8) cnt[tid]=0;
  __syncthreads();
  for (int i=tid;i<NTOK*2;i+=256) atomicAdd(&cnt[topi[i]],1);
  __syncthreads();
  if (tid==0){
    int s=0;
    for (int e=0;e<8;e++){ offs[e]=s; s+=cnt[e]; }
    offs[8]=s;
    for (int e=0;e<9;e++) off[e]=offs[e];
  }
  __syncthreads();
  if (tid<8) cur[tid]=offs[tid];
  __syncthreads();
  for (int i=tid;i<NTOK*2;i+=256){
    int e = topi[i];
    int pos = atomicAdd(&cur[e],1);
    perm[pos] = i>>1;
    pw[pos]   = topw[i];
  }
}

// ---------------- MoE stage1: H = silu(Xg@W1+b1) * (Xg@W2+b2), gathered rows ----------------
__global__ __launch_bounds__(256) void k_moe1(
    const u16* __restrict__ hn,
    const u16* __restrict__ W1, const float* __restrict__ b1,
    const u16* __restrict__ W2, const float* __restrict__ b2,
    const int* __restrict__ off, const int* __restrict__ perm,
    u16* __restrict__ H)
{
  int e = blockIdx.z;
  int base = off[e], cnte = off[e+1]-off[e];
  int mt = blockIdx.y;
  if (mt*64 >= cnte) return;
  int n0 = blockIdx.x*64;
  __shared__ u16 As[64*32];
  __shared__ u16 B1s[32*BPAD];
  __shared__ u16 B2s[32*BPAD];
  __shared__ int toks[64];
  int tid = threadIdx.x;
  int wave = tid>>6, lane = tid&63, l15 = lane&15, q = lane>>4;
  int ar = tid>>2, ac = (tid&3)*8;
  int bkr = tid>>3, bnc = (tid&7)*8;
  if (tid < 64){
    int r = mt*64 + tid;
    toks[tid] = (r < cnte) ? perm[base+r] : -1;
  }
  const u16* B1 = W1 + (size_t)e*D_MODEL*D_FF;
  const u16* B2 = W2 + (size_t)e*D_MODEL*D_FF;
  floatx4 acc1[4], acc2[4];
  #pragma unroll
  for (int t=0;t<4;t++){ acc1[t]=(floatx4){0.f,0.f,0.f,0.f}; acc2[t]=(floatx4){0.f,0.f,0.f,0.f}; }
  __syncthreads();
  for (int k0=0;k0<D_MODEL;k0+=32){
    __syncthreads();
    int t = toks[ar];
    uint4 av = {0,0,0,0};
    if (t >= 0) av = *(const uint4*)(hn + (size_t)t*D_MODEL + k0 + ac);
    *(uint4*)&As[ar*32+ac] = av;
    uint4 b1v = *(const uint4*)(B1 + (size_t)(k0+bkr)*D_FF + n0 + bnc);
    uint4 b2v = *(const uint4*)(B2 + (size_t)(k0+bkr)*D_FF + n0 + bnc);
    u32* w1p = (u32*)&B1s[bkr*BPAD + bnc];
    w1p[0]=b1v.x; w1p[1]=b1v.y; w1p[2]=b1v.z; w1p[3]=b1v.w;
    u32* w2p = (u32*)&B2s[bkr*BPAD + bnc];
    w2p[0]=b2v.x; w2p[1]=b2v.y; w2p[2]=b2v.z; w2p[3]=b2v.w;
    __syncthreads();
    short8 af = *(const short8*)&As[(wave*16 + l15)*32 + q*8];
    #pragma unroll
    for (int tt=0;tt<4;tt++){
      short8 bf1, bf2;
      #pragma unroll
      for (int j=0;j<8;j++){
        bf1[j] = (short)B1s[(q*8+j)*BPAD + tt*16 + l15];
        bf2[j] = (short)B2s[(q*8+j)*BPAD + tt*16 + l15];
      }
      acc1[tt] = mfma16(af, bf1, acc1[tt]);
      acc2[tt] = mfma16(af, bf2, acc2[tt]);
    }
  }
  #pragma unroll
  for (int tt=0;tt<4;tt++){
    #pragma unroll
    for (int r=0;r<4;r++){
      int rloc = wave*16 + q*4 + r;
      if (mt*64 + rloc < cnte){
        int col = n0 + tt*16 + l15;
        float h1 = acc1[tt][r] + b1[e*D_FF+col];
        float h2 = acc2[tt][r] + b2[e*D_FF+col];
        float sil = h1 / (1.f + __expf(-h1));
        H[(size_t)(base + mt*64 + rloc)*D_FF + col] = f2bf(h2*sil);
      }
    }
  }
}

// ---------------- MoE stage2: acc[token] += w * (H@W3 + b3) ----------------
__global__ __launch_bounds__(256) void k_moe2(
    const u16* __restrict__ H, const u16* __restrict__ W3, const float* __restrict__ b3,
    const int* __restrict__ off, const int* __restrict__ perm, const float* __restrict__ pw,
    float* __restrict__ accb)
{
  int e = blockIdx.z;
  int base = off[e], cnte = off[e+1]-off[e];
  int mt = blockIdx.y;
  if (mt*64 >= cnte) return;
  int n0 = blockIdx.x*64;
  __shared__ u16 As[64*32];
  __shared__ u16 Bs[32*BPAD];
  int tid = threadIdx.x;
  int wave = tid>>6, lane = tid&63, l15 = lane&15, q = lane>>4;
  int ar = tid>>2, ac = (tid&3)*8;
  int bkr = tid>>3, bnc = (tid&7)*8;
  const u16* B = W3 + (size_t)e*D_FF*D_MODEL;
  floatx4 acc[4];
  #pragma unroll
  for (int t=0;t<4;t++) acc[t] = (floatx4){0.f,0.f,0.f,0.f};
  for (int k0=0;k0<D_FF;k0+=32){
    __syncthreads();
    int grow = mt*64 + ar;
    uint4 av = {0,0,0,0};
    if (grow < cnte) av = *(const uint4*)(H + (size_t)(base+grow)*D_FF + k0 + ac);
    *(uint4*)&As[ar*32+ac] = av;
    uint4 bv = *(const uint4*)(B + (size_t)(k0+bkr)*D_MODEL + n0 + bnc);
    u32* bw = (u32*)&Bs[bkr*BPAD + bnc];
    bw[0]=bv.x; bw[1]=bv.y; bw[2]=bv.z; bw[3]=bv.w;
    __syncthreads();
    short8 af = *(const short8*)&As[(wave*16 + l15)*32 + q*8];
    #pragma unroll
    for (int t=0;t<4;t++){
      short8 bf;
      #pragma unroll
      for (int j=0;j<8;j++) bf[j] = (short)Bs[(q*8+j)*BPAD + t*16 + l15];
      acc[t] = mfma16(af, bf, acc[t]);
    }
  }
  #pragma unroll
  for (int t=0;t<4;t++){
    #pragma unroll
    for (int r=0;r<4;r++){
      int rloc = wave*16 + q*4 + r;
      int grow = mt*64 + rloc;
      if (grow < cnte){
        int col = n0 + t*16 + l15;
        int tok = perm[base+grow];
        float wgt = pw[base+grow];
        float val = acc[t][r] + b3[e*D_MODEL+col];
        atomicAdd(accb + (size_t)tok*D_MODEL + col, wgt*val);
      }
    }
  }
}

// ---------------- finalize: out = fp32 acc ----------------
__global__ __launch_bounds__(256) void k_final(const float* __restrict__ accb, float* __restrict__ out)
{
  int i = blockIdx.x*256 + threadIdx.x;       // 4 elems per thread
  ((float4*)out)[i] = ((const float4*)accb)[i];
}

extern "C" void kernel_launch(void* const* d_in, const int* in_sizes, int n_in,
                              void* d_out, int out_size, void* d_ws, size_t ws_size,
                              hipStream_t stream)
{
  const float* x   = (const float*)d_in[0];
  const float* n1w = (const float*)d_in[1];
  const float* Wq  = (const float*)d_in[2];
  const float* Wk  = (const float*)d_in[3];
  const float* Wv  = (const float*)d_in[4];
  const float* Wo  = (const float*)d_in[5];
  const float* n2w = (const float*)d_in[6];
  const float* rw  = (const float*)d_in[7];
  const float* rb  = (const float*)d_in[8];
  const float* W1  = (const float*)d_in[9];
  const float* b1  = (const float*)d_in[10];
  const float* W2  = (const float*)d_in[11];
  const float* b2  = (const float*)d_in[12];
  const float* W3  = (const float*)d_in[13];
  const float* b3  = (const float*)d_in[14];
  float* out = (float*)d_out;

  char* p = (char*)d_ws;
  auto alloc = [&](size_t bytes)->char*{
    char* r = p; p += (bytes + 255) & ~(size_t)255; return r;
  };
  u16*   xr   = (u16*)  alloc((size_t)NTOK*D_MODEL*2);
  u16*   Qb   = (u16*)  alloc((size_t)NTOK*D_MODEL*2);
  u16*   Kb   = (u16*)  alloc((size_t)NTOK*KVD*2);
  u16*   Vb   = (u16*)  alloc((size_t)NTOK*KVD*2);
  u16*   Vt   = (u16*)  alloc((size_t)NTOK*KVD*2);   // transposed V: [b][g][d][s]
  u16*   attn = (u16*)  alloc((size_t)NTOK*D_MODEL*2);
  u16*   hn   = (u16*)  alloc((size_t)NTOK*D_MODEL*2);
  float* acc  = (float*)alloc((size_t)NTOK*D_MODEL*4);
  int*   topi = (int*)  alloc((size_t)NTOK*2*4);
  float* topw = (float*)alloc((size_t)NTOK*2*4);
  int*   off  = (int*)  alloc(64);
  int*   perm = (int*)  alloc((size_t)NTOK*2*4);
  float* pw   = (float*)alloc((size_t)NTOK*2*4);
  u16*   H    = (u16*)  alloc((size_t)NTOK*2*D_FF*2);
  // bf16 weight copies
  u16*   Wqb  = (u16*)  alloc((size_t)D_MODEL*D_MODEL*2);
  u16*   Wkb  = (u16*)  alloc((size_t)D_MODEL*KVD*2);
  u16*   Wvb  = (u16*)  alloc((size_t)D_MODEL*KVD*2);
  u16*   Wob  = (u16*)  alloc((size_t)D_MODEL*D_MODEL*2);
  u16*   W1b  = (u16*)  alloc((size_t)N_EXPERTS*D_MODEL*D_FF*2);
  u16*   W2b  = (u16*)  alloc((size_t)N_EXPERTS*D_MODEL*D_FF*2);
  u16*   W3b  = (u16*)  alloc((size_t)N_EXPERTS*D_FF*D_MODEL*2);

  auto cvt = [&](const float* src, u16* dst, size_t n){
    int n4 = (int)(n/4);
    k_cvt<<<(n4+255)/256, 256, 0, stream>>>(src, dst, n4);
  };
  // 0. weight conversion fp32 -> bf16
  cvt(Wq, Wqb, (size_t)D_MODEL*D_MODEL);
  cvt(Wk, Wkb, (size_t)D_MODEL*KVD);
  cvt(Wv, Wvb, (size_t)D_MODEL*KVD);
  cvt(Wo, Wob, (size_t)D_MODEL*D_MODEL);
  cvt(W1, W1b, (size_t)N_EXPERTS*D_MODEL*D_FF);
  cvt(W2, W2b, (size_t)N_EXPERTS*D_MODEL*D_FF);
  cvt(W3, W3b, (size_t)N_EXPERTS*D_FF*D_MODEL);

  // 1. norm1 + rope
  k_rmsnorm_rope<<<NTOK, 256, 0, stream>>>(x, n1w, xr);
  // 2. Q,K,V projections
  k_gemm<<<dim3(D_MODEL/64, NTOK/64), 256, 0, stream>>>(xr, Wqb, Qb, NTOK, D_MODEL, D_MODEL);
  k_gemm<<<dim3(KVD/64,     NTOK/64), 256, 0, stream>>>(xr, Wkb, Kb, NTOK, KVD, D_MODEL);
  k_gemm<<<dim3(KVD/64,     NTOK/64), 256, 0, stream>>>(xr, Wvb, Vb, NTOK, KVD, D_MODEL);
  // 3. attention (flash, MFMA)
  k_vtrans<<<dim3(SEQ/64, BATCH*N_GROUPS), 256, 0, stream>>>(Vb, Vt);
  k_attn_flash<<<dim3(SEQ/64, N_HEADS, BATCH), 256, 0, stream>>>(Qb, Kb, Vt, attn);
  // 4. out proj + residual -> h (fp32)
  k_gemm_resid<<<dim3(D_MODEL/64, NTOK/64), 256, 0, stream>>>(attn, Wob, x, acc, NTOK, D_MODEL, D_MODEL);
  // 5. norm2 (bf16 activations for expert GEMMs)
  k_rmsnorm2<<<NTOK, 256, 0, stream>>>(acc, n2w, hn);
  // 6. router (fp32, from fp32 residual) + pack
  k_router<<<NTOK, 64, 0, stream>>>(acc, n2w, rw, rb, topi, topw);
  k_pack<<<1, 256, 0, stream>>>(topi, topw, off, perm, pw);
  // 7. expert FFN
  k_moe1<<<dim3(D_FF/64, 32, N_EXPERTS), 256, 0, stream>>>(hn, W1b, b1, W2b, b2, off, perm, H);
  k_moe2<<<dim3(D_MODEL/64, 32, N_EXPERTS), 256, 0, stream>>>(H, W3b, b3, off, perm, pw, acc);
  // 8. finalize
  k_final<<<(NTOK*D_MODEL/4)/256, 256, 0, stream>>>(acc, out);
}